// Round 1
// baseline (2385.814 us; speedup 1.0000x reference)
//
#include <hip/hip_runtime.h>
#include <math.h>

// Problem constants
// B=4, N=2048 (q and kv), H=8, CM=8, CS=16, IN_MV=16, IN_S=32, OUT_MV=16, OUT_S=32
// head feature dim D = CM*16 + CS = 144; softmax scale = 1/sqrt(144) = 1/12

constexpr int   kG[16]   = {0,1,1,1,1,2,2,2,2,2,2,3,3,3,3,4};
constexpr float kEta[16] = {1.f,1.f,-1.f,-1.f,-1.f,-1.f,-1.f,-1.f,1.f,1.f,1.f,1.f,1.f,1.f,-1.f,-1.f};
#define ATT_SCALE (1.0f/12.0f)

// ---------------------------------------------------------------------------
// Kernel 1: Q projection. One block per token (192 threads: 64 mv-out rows +
// 128 scalar-out rows). Writes qf in (B,H,N,144) layout with ETA and the
// softmax scale folded in.
// ---------------------------------------------------------------------------
__global__ __launch_bounds__(192) void k_proj_q(
    const float* __restrict__ mv, const float* __restrict__ sc,
    const float* __restrict__ w_mv, const float* __restrict__ w_s2mv,
    const float* __restrict__ w_mv2s, const float* __restrict__ w_s,
    float* __restrict__ qf)
{
  __shared__ float lmv[256];
  __shared__ float ls[32];
  const int tok = blockIdx.x;            // b*2048 + n
  const int b = tok >> 11, n = tok & 2047;
  const int t = threadIdx.x;
  const float* mvp = mv + (size_t)tok * 256;
  for (int i = t; i < 256; i += 192) lmv[i] = mvp[i];
  if (t < 32) ls[t] = sc[(size_t)tok * 32 + t];
  __syncthreads();

  if (t < 64) {
    const int o = t;                     // mv out channel, o = c*8 + h
    float acc[16];
    #pragma unroll
    for (int x = 0; x < 16; ++x) acc[x] = 0.f;
    #pragma unroll 4
    for (int i = 0; i < 16; ++i) {
      float wg[5];
      #pragma unroll
      for (int g = 0; g < 5; ++g) wg[g] = w_mv[(g*64 + o)*16 + i];
      const float* mr = &lmv[i*16];
      #pragma unroll
      for (int x = 0; x < 16; ++x) acc[x] += mr[x] * wg[kG[x]];
    }
    float a0 = 0.f;
    #pragma unroll 8
    for (int j = 0; j < 32; ++j) a0 += ls[j] * w_s2mv[o*32 + j];
    acc[0] += a0;
    const int c = o >> 3, h = o & 7;
    float* dst = qf + (((size_t)(b*8 + h)*2048 + n)*144 + c*16);
    #pragma unroll
    for (int x = 0; x < 16; ++x) dst[x] = acc[x] * kEta[x] * ATT_SCALE;
  } else {
    const int o2 = t - 64;               // scalar out channel, o2 = cs*8 + h
    float a = 0.f;
    #pragma unroll 8
    for (int j = 0; j < 32; ++j) a += ls[j] * w_s[o2*32 + j];
    #pragma unroll 8
    for (int i = 0; i < 16; ++i) a += lmv[i*16] * w_mv2s[o2*16 + i];
    const int cs = o2 >> 3, h = o2 & 7;
    qf[((size_t)(b*8 + h)*2048 + n)*144 + 128 + cs] = a * ATT_SCALE;
  }
}

// ---------------------------------------------------------------------------
// Kernel 2: KV projection. One block per token (384 threads: 128 mv-out +
// 256 scalar-out). K = mv channels [0,64) & scalar [0,128); V = the rest.
// ---------------------------------------------------------------------------
__global__ __launch_bounds__(384) void k_proj_kv(
    const float* __restrict__ mv, const float* __restrict__ sc,
    const float* __restrict__ w_mv, const float* __restrict__ w_s2mv,
    const float* __restrict__ w_mv2s, const float* __restrict__ w_s,
    float* __restrict__ kf, float* __restrict__ vf)
{
  __shared__ float lmv[256];
  __shared__ float ls[32];
  const int tok = blockIdx.x;
  const int b = tok >> 11, n = tok & 2047;
  const int t = threadIdx.x;
  const float* mvp = mv + (size_t)tok * 256;
  for (int i = t; i < 256; i += 384) lmv[i] = mvp[i];
  if (t < 32) ls[t] = sc[(size_t)tok * 32 + t];
  __syncthreads();

  if (t < 128) {
    const int o = t;
    float acc[16];
    #pragma unroll
    for (int x = 0; x < 16; ++x) acc[x] = 0.f;
    #pragma unroll 4
    for (int i = 0; i < 16; ++i) {
      float wg[5];
      #pragma unroll
      for (int g = 0; g < 5; ++g) wg[g] = w_mv[(g*128 + o)*16 + i];
      const float* mr = &lmv[i*16];
      #pragma unroll
      for (int x = 0; x < 16; ++x) acc[x] += mr[x] * wg[kG[x]];
    }
    float a0 = 0.f;
    #pragma unroll 8
    for (int j = 0; j < 32; ++j) a0 += ls[j] * w_s2mv[o*32 + j];
    acc[0] += a0;
    const int isv = o >> 6;              // 0 = K, 1 = V
    const int oo = o & 63;
    const int c = oo >> 3, h = oo & 7;
    float* dst = (isv ? vf : kf) + (((size_t)(b*8 + h)*2048 + n)*144 + c*16);
    #pragma unroll
    for (int x = 0; x < 16; ++x) dst[x] = acc[x];
  } else {
    const int o2 = t - 128;              // 0..255
    float a = 0.f;
    #pragma unroll 8
    for (int j = 0; j < 32; ++j) a += ls[j] * w_s[o2*32 + j];
    #pragma unroll 8
    for (int i = 0; i < 16; ++i) a += lmv[i*16] * w_mv2s[o2*16 + i];
    const int isv = o2 >> 7;             // 0 = K, 1 = V
    const int oo = o2 & 127;
    const int cs = oo >> 3, h = oo & 7;
    (isv ? vf : kf)[((size_t)(b*8 + h)*2048 + n)*144 + 128 + cs] = a;
  }
}

// ---------------------------------------------------------------------------
// Kernel 3: flash attention, f32 vector-ALU. One block = (b, h, 32 queries).
// 256 threads as 16x16 grid; thread (ty,tx) owns q rows 2ty..2ty+1 and
// k cols 2tx..2tx+1 of the 32x32 score tile; O accumulators are 2 rows x
// 9 columns (d = tx + 16u). K is staged transposed in LDS.
// LDS: 18944 + 18432 + 18944 + 4224 = 60544 B -> 2 blocks/CU.
// ---------------------------------------------------------------------------
__global__ __launch_bounds__(256) void k_attn(
    const float* __restrict__ qf, const float* __restrict__ kf,
    const float* __restrict__ vf, const float* __restrict__ hsc,
    float* __restrict__ ho)
{
  __shared__ float Qs[32][148];
  __shared__ float Ks[144][32];   // transposed: Ks[d][kj]
  __shared__ float Vs[32][148];
  __shared__ float Ps[32][33];

  const int bid = blockIdx.x;
  const int qt = bid & 63;
  const int h  = (bid >> 6) & 7;
  const int b  = bid >> 9;
  const int t  = threadIdx.x;
  const int tx = t & 15, ty = t >> 4;

  const float* qb = qf + ((size_t)(b*8 + h)*2048 + qt*32) * 144;
  const float* kb = kf + (size_t)(b*8 + h)*2048 * 144;
  const float* vb = vf + (size_t)(b*8 + h)*2048 * 144;

  for (int idx = t; idx < 32*36; idx += 256) {
    const int row = idx / 36, d4 = idx - row*36;
    *(float4*)&Qs[row][d4*4] = *(const float4*)&qb[(size_t)row*144 + d4*4];
  }

  float o0[9], o1[9];
  #pragma unroll
  for (int u = 0; u < 9; ++u) { o0[u] = 0.f; o1[u] = 0.f; }
  float m0 = -INFINITY, m1 = -INFINITY, l0 = 0.f, l1 = 0.f;

  for (int kt = 0; kt < 64; ++kt) {
    __syncthreads();  // prev PV done (and Q staged on first iter)
    // stage K transposed: conflict-free LDS writes (consecutive lanes -> consecutive kj)
    for (int idx = t; idx < 32*36; idx += 256) {
      const int kj = idx & 31, d4 = idx >> 5;
      const float4 k4 = *(const float4*)&kb[((size_t)kt*32 + kj)*144 + d4*4];
      Ks[d4*4+0][kj] = k4.x;
      Ks[d4*4+1][kj] = k4.y;
      Ks[d4*4+2][kj] = k4.z;
      Ks[d4*4+3][kj] = k4.w;
    }
    // stage V row-major (coalesced global, aligned b128 LDS writes)
    for (int idx = t; idx < 32*36; idx += 256) {
      const int row = idx / 36, d4 = idx - row*36;
      *(float4*)&Vs[row][d4*4] = *(const float4*)&vb[((size_t)kt*32 + row)*144 + d4*4];
    }
    __syncthreads();

    // scores: 2x2 per thread over D=144
    float s00 = 0.f, s01 = 0.f, s10 = 0.f, s11 = 0.f;
    #pragma unroll 4
    for (int d0 = 0; d0 < 144; d0 += 4) {
      const float4 q0 = *(const float4*)&Qs[ty*2+0][d0];
      const float4 q1 = *(const float4*)&Qs[ty*2+1][d0];
      const float* q0p = (const float*)&q0;
      const float* q1p = (const float*)&q1;
      #pragma unroll
      for (int j = 0; j < 4; ++j) {
        const float2 kd = *(const float2*)&Ks[d0+j][tx*2];
        s00 += q0p[j]*kd.x; s01 += q0p[j]*kd.y;
        s10 += q1p[j]*kd.x; s11 += q1p[j]*kd.y;
      }
    }

    // online softmax; rows live in contiguous 16-lane groups
    float tm0 = fmaxf(s00, s01), tm1 = fmaxf(s10, s11);
    #pragma unroll
    for (int off = 1; off < 16; off <<= 1) {
      tm0 = fmaxf(tm0, __shfl_xor(tm0, off));
      tm1 = fmaxf(tm1, __shfl_xor(tm1, off));
    }
    const float mn0 = fmaxf(m0, tm0), mn1 = fmaxf(m1, tm1);
    const float r0 = __expf(m0 - mn0), r1 = __expf(m1 - mn1);
    const float p00 = __expf(s00 - mn0), p01 = __expf(s01 - mn0);
    const float p10 = __expf(s10 - mn1), p11 = __expf(s11 - mn1);
    Ps[ty*2+0][tx*2+0] = p00; Ps[ty*2+0][tx*2+1] = p01;
    Ps[ty*2+1][tx*2+0] = p10; Ps[ty*2+1][tx*2+1] = p11;
    float ts0 = p00 + p01, ts1 = p10 + p11;
    #pragma unroll
    for (int off = 1; off < 16; off <<= 1) {
      ts0 += __shfl_xor(ts0, off);
      ts1 += __shfl_xor(ts1, off);
    }
    l0 = l0*r0 + ts0; l1 = l1*r1 + ts1;
    #pragma unroll
    for (int u = 0; u < 9; ++u) { o0[u] *= r0; o1[u] *= r1; }
    m0 = mn0; m1 = mn1;
    __syncthreads();  // Ps visible

    // PV: O[qi][tx+16u] += sum_kj P[qi][kj] * V[kj][tx+16u]
    #pragma unroll 4
    for (int kj = 0; kj < 32; ++kj) {
      const float pa = Ps[ty*2+0][kj], pb = Ps[ty*2+1][kj];
      #pragma unroll
      for (int u = 0; u < 9; ++u) {
        const float v = Vs[kj][tx + 16*u];
        o0[u] += pa*v; o1[u] += pb*v;
      }
    }
  }

  const float hs = hsc[h];
  const float i0 = hs / l0, i1 = hs / l1;
  // ho layout: (B, N, H, 144) -> merged-head friendly for the O projection
  float* d0p = ho + (((size_t)(b*2048 + qt*32 + ty*2 + 0))*8 + h)*144;
  float* d1p = d0p + 8*144;
  #pragma unroll
  for (int u = 0; u < 9; ++u) {
    d0p[tx + 16*u] = o0[u]*i0;
    d1p[tx + 16*u] = o1[u]*i1;
  }
}

// ---------------------------------------------------------------------------
// Kernel 4: output projection. One block (64 threads) per token; threads
// 0..15 produce the 16 mv output rows, 16..47 the 32 scalar outputs.
// ---------------------------------------------------------------------------
__global__ __launch_bounds__(64) void k_out(
    const float* __restrict__ ho,
    const float* __restrict__ w_mv, const float* __restrict__ w_s2mv,
    const float* __restrict__ w_mv2s, const float* __restrict__ w_s,
    float* __restrict__ out)
{
  __shared__ float lh[1152];   // 8 heads * 144
  const int tok = blockIdx.x;
  const int t = threadIdx.x;
  const float* hp = ho + (size_t)tok * 1152;
  for (int idx = t; idx < 288; idx += 64)
    *(float4*)&lh[idx*4] = *(const float4*)&hp[idx*4];
  __syncthreads();

  if (t < 16) {
    const int o = t;
    float acc[16];
    #pragma unroll
    for (int x = 0; x < 16; ++x) acc[x] = 0.f;
    for (int mc = 0; mc < 64; ++mc) {   // merged mv channel = h*8 + c
      float wg[5];
      #pragma unroll
      for (int g = 0; g < 5; ++g) wg[g] = w_mv[(g*16 + o)*64 + mc];
      const float* hr = &lh[(mc >> 3)*144 + (mc & 7)*16];
      #pragma unroll
      for (int x = 0; x < 16; ++x) acc[x] += hr[x]*wg[kG[x]];
    }
    float a0 = 0.f;
    for (int s = 0; s < 128; ++s)       // merged scalar channel = h*16 + cs
      a0 += lh[(s >> 4)*144 + 128 + (s & 15)] * w_s2mv[o*128 + s];
    acc[0] += a0;
    float* op = out + (size_t)tok*256 + o*16;
    #pragma unroll
    for (int x = 0; x < 16; ++x) op[x] = acc[x];
  } else if (t < 48) {
    const int o2 = t - 16;
    float a = 0.f;
    for (int s = 0; s < 128; ++s)
      a += lh[(s >> 4)*144 + 128 + (s & 15)] * w_s[o2*128 + s];
    for (int mc = 0; mc < 64; ++mc)
      a += lh[(mc >> 3)*144 + (mc & 7)*16] * w_mv2s[o2*64 + mc];
    out[2097152 + (size_t)tok*32 + o2] = a;   // mv out block = 4*2048*256
  }
}

// ---------------------------------------------------------------------------
extern "C" void kernel_launch(void* const* d_in, const int* in_sizes, int n_in,
                              void* d_out, int out_size, void* d_ws, size_t ws_size,
                              hipStream_t stream) {
  const float* mv_kv    = (const float*)d_in[0];
  const float* mv_q     = (const float*)d_in[1];
  const float* s_kv     = (const float*)d_in[2];
  const float* s_q      = (const float*)d_in[3];
  const float* w_mv_q   = (const float*)d_in[4];
  const float* w_s2mv_q = (const float*)d_in[5];
  const float* w_mv2s_q = (const float*)d_in[6];
  const float* w_s_q    = (const float*)d_in[7];
  const float* w_mv_kv   = (const float*)d_in[8];
  const float* w_s2mv_kv = (const float*)d_in[9];
  const float* w_mv2s_kv = (const float*)d_in[10];
  const float* w_s_kv    = (const float*)d_in[11];
  const float* w_mv_o   = (const float*)d_in[12];
  const float* w_s2mv_o = (const float*)d_in[13];
  const float* w_mv2s_o = (const float*)d_in[14];
  const float* w_s_o    = (const float*)d_in[15];
  const float* hscale   = (const float*)d_in[16];

  // workspace: qf, kf, vf (B,H,N,144) + ho (B,N,H,144), all f32
  // 4 * 9,437,184 floats = 150,994,944 bytes needed in d_ws
  float* ws = (float*)d_ws;
  const size_t SZ = (size_t)4 * 8 * 2048 * 144;
  float* qf = ws;
  float* kf = ws + SZ;
  float* vf = ws + 2*SZ;
  float* ho = ws + 3*SZ;

  k_proj_q <<<8192, 192, 0, stream>>>(mv_q,  s_q,  w_mv_q,  w_s2mv_q,  w_mv2s_q,  w_s_q,  qf);
  k_proj_kv<<<8192, 384, 0, stream>>>(mv_kv, s_kv, w_mv_kv, w_s2mv_kv, w_mv2s_kv, w_s_kv, kf, vf);
  k_attn   <<<2048, 256, 0, stream>>>(qf, kf, vf, hscale, ho);
  k_out    <<<8192, 64, 0, stream>>>(ho, w_mv_o, w_s2mv_o, w_mv2s_o, w_s_o, (float*)d_out);
}

// Round 2
// 383.852 us; speedup vs baseline: 6.2154x; 6.2154x over previous
//
#include <hip/hip_runtime.h>
#include <math.h>

// B=4, N=2048, H=8, CM=8, CS=16 ; head dim 144 padded to 160 (5 chunks of 32)
// qf/kf/vf: bf16 (b,h,n,160); ho: f32 (b,n,h,144)

typedef float f32x4 __attribute__((ext_vector_type(4)));
typedef __bf16 bf16x8 __attribute__((ext_vector_type(8)));
typedef unsigned short u16;
typedef unsigned int u32;

constexpr int   kG[16]   = {0,1,1,1,1,2,2,2,2,2,2,3,3,3,3,4};
constexpr float kEta[16] = {1.f,1.f,-1.f,-1.f,-1.f,-1.f,-1.f,-1.f,1.f,1.f,1.f,1.f,1.f,1.f,-1.f,-1.f};
#define ATT_SCALE (1.0f/12.0f)

__device__ __forceinline__ u32 pack2(float a, float b) {
  u32 ua = __builtin_bit_cast(u32, a);
  u32 ub = __builtin_bit_cast(u32, b);
  ua = (ua + 0x7fffu + ((ua >> 16) & 1u)) >> 16;
  ub = (ub + 0x7fffu + ((ub >> 16) & 1u)) >> 16;
  return ua | (ub << 16);
}
__device__ __forceinline__ u16 bf16of(float a) { return (u16)(pack2(a, 0.f) & 0xffffu); }

__device__ __forceinline__ f32x4 mfma_bf16(uint4 a, uint4 b, f32x4 c) {
  return __builtin_amdgcn_mfma_f32_16x16x32_bf16(
      __builtin_bit_cast(bf16x8, a), __builtin_bit_cast(bf16x8, b), c, 0, 0, 0);
}

// ---------------------------------------------------------------------------
// Q projection -> bf16 qf (b,h,n,160), ETA & 1/12 folded, pad zeroed
// ---------------------------------------------------------------------------
__global__ __launch_bounds__(192) void k_proj_q(
    const float* __restrict__ mv, const float* __restrict__ sc,
    const float* __restrict__ w_mv, const float* __restrict__ w_s2mv,
    const float* __restrict__ w_mv2s, const float* __restrict__ w_s,
    u16* __restrict__ qf)
{
  __shared__ float lmv[256];
  __shared__ float ls[32];
  const int tok = blockIdx.x;
  const int b = tok >> 11, n = tok & 2047;
  const int t = threadIdx.x;
  const float* mvp = mv + (size_t)tok * 256;
  for (int i = t; i < 256; i += 192) lmv[i] = mvp[i];
  if (t < 32) ls[t] = sc[(size_t)tok * 32 + t];
  __syncthreads();

  if (t < 64) {
    const int o = t;                     // o = c*8 + h
    float acc[16];
    #pragma unroll
    for (int x = 0; x < 16; ++x) acc[x] = 0.f;
    #pragma unroll 4
    for (int i = 0; i < 16; ++i) {
      float wg[5];
      #pragma unroll
      for (int g = 0; g < 5; ++g) wg[g] = w_mv[(g*64 + o)*16 + i];
      const float* mr = &lmv[i*16];
      #pragma unroll
      for (int x = 0; x < 16; ++x) acc[x] += mr[x] * wg[kG[x]];
    }
    float a0 = 0.f;
    #pragma unroll 8
    for (int j = 0; j < 32; ++j) a0 += ls[j] * w_s2mv[o*32 + j];
    acc[0] += a0;
    const int c = o >> 3, h = o & 7;
    u16* dst = qf + ((size_t)(b*8 + h)*2048 + n)*160;
    u32 u[8];
    #pragma unroll
    for (int p = 0; p < 8; ++p)
      u[p] = pack2(acc[2*p]*kEta[2*p]*ATT_SCALE, acc[2*p+1]*kEta[2*p+1]*ATT_SCALE);
    *(uint4*)(dst + c*16)     = uint4{u[0],u[1],u[2],u[3]};
    *(uint4*)(dst + c*16 + 8) = uint4{u[4],u[5],u[6],u[7]};
    *(u32*)(dst + 144 + c*2) = 0u;       // zero pad d=144..159
  } else {
    const int o2 = t - 64;               // o2 = cs*8 + h
    float a = 0.f;
    #pragma unroll 8
    for (int j = 0; j < 32; ++j) a += ls[j] * w_s[o2*32 + j];
    #pragma unroll 8
    for (int i = 0; i < 16; ++i) a += lmv[i*16] * w_mv2s[o2*16 + i];
    const int cs = o2 >> 3, h = o2 & 7;
    qf[((size_t)(b*8 + h)*2048 + n)*160 + 128 + cs] = bf16of(a * ATT_SCALE);
  }
}

// ---------------------------------------------------------------------------
// KV projection -> bf16 kf, vf (b,h,n,160), pads zeroed
// ---------------------------------------------------------------------------
__global__ __launch_bounds__(384) void k_proj_kv(
    const float* __restrict__ mv, const float* __restrict__ sc,
    const float* __restrict__ w_mv, const float* __restrict__ w_s2mv,
    const float* __restrict__ w_mv2s, const float* __restrict__ w_s,
    u16* __restrict__ kf, u16* __restrict__ vf)
{
  __shared__ float lmv[256];
  __shared__ float ls[32];
  const int tok = blockIdx.x;
  const int b = tok >> 11, n = tok & 2047;
  const int t = threadIdx.x;
  const float* mvp = mv + (size_t)tok * 256;
  for (int i = t; i < 256; i += 384) lmv[i] = mvp[i];
  if (t < 32) ls[t] = sc[(size_t)tok * 32 + t];
  __syncthreads();

  if (t < 128) {
    const int o = t;
    float acc[16];
    #pragma unroll
    for (int x = 0; x < 16; ++x) acc[x] = 0.f;
    #pragma unroll 4
    for (int i = 0; i < 16; ++i) {
      float wg[5];
      #pragma unroll
      for (int g = 0; g < 5; ++g) wg[g] = w_mv[(g*128 + o)*16 + i];
      const float* mr = &lmv[i*16];
      #pragma unroll
      for (int x = 0; x < 16; ++x) acc[x] += mr[x] * wg[kG[x]];
    }
    float a0 = 0.f;
    #pragma unroll 8
    for (int j = 0; j < 32; ++j) a0 += ls[j] * w_s2mv[o*32 + j];
    acc[0] += a0;
    const int isv = o >> 6;
    const int oo = o & 63;
    const int c = oo >> 3, h = oo & 7;
    u16* dst = (isv ? vf : kf) + ((size_t)(b*8 + h)*2048 + n)*160;
    u32 u[8];
    #pragma unroll
    for (int p = 0; p < 8; ++p) u[p] = pack2(acc[2*p], acc[2*p+1]);
    *(uint4*)(dst + c*16)     = uint4{u[0],u[1],u[2],u[3]};
    *(uint4*)(dst + c*16 + 8) = uint4{u[4],u[5],u[6],u[7]};
    *(u32*)(dst + 144 + c*2) = 0u;
  } else {
    const int o2 = t - 128;
    float a = 0.f;
    #pragma unroll 8
    for (int j = 0; j < 32; ++j) a += ls[j] * w_s[o2*32 + j];
    #pragma unroll 8
    for (int i = 0; i < 16; ++i) a += lmv[i*16] * w_mv2s[o2*16 + i];
    const int isv = o2 >> 7;
    const int oo = o2 & 127;
    const int cs = oo >> 3, h = oo & 7;
    (isv ? vf : kf)[((size_t)(b*8 + h)*2048 + n)*160 + 128 + cs] = bf16of(a);
  }
}

// ---------------------------------------------------------------------------
// Flash attention with bf16 MFMA. Block = (bh, 64 q rows), 4 waves x 16 rows.
// Swapped QK^T (S^T = K*Q^T) keeps P lane-local for PV (O^T = V^T * P^T).
// LDS: Ks[64][168] bf16 (21504 B) + Vt[160][72] bf16 (23040 B) = 44544 B.
// ---------------------------------------------------------------------------
__global__ __launch_bounds__(256, 3) void k_attn(
    const u16* __restrict__ qf, const u16* __restrict__ kf,
    const u16* __restrict__ vf, const float* __restrict__ hsc,
    float* __restrict__ ho)
{
  __shared__ __align__(16) char smem[44544];
  u16 (*Ks)[168] = reinterpret_cast<u16(*)[168]>(smem);
  u16 (*Vt)[72]  = reinterpret_cast<u16(*)[72]>(smem + 21504);

  const int bid = blockIdx.x;
  const int qt = bid & 31;
  const int bh = bid >> 5;
  const int h  = bh & 7;
  const int b  = bh >> 3;
  const int t  = threadIdx.x;
  const int w  = t >> 6;
  const int lane = t & 63;
  const int qi = lane & 15;      // q row (B-col) / k row (A-row) / d row in PV
  const int hi = lane >> 4;

  const u16* kg = kf + (size_t)bh * 2048 * 160;
  const u16* vg = vf + (size_t)bh * 2048 * 160;
  const u16* qg = qf + ((size_t)bh * 2048 + qt*64 + w*16) * 160;

  // Q fragments (B-operand layout): lane holds Q[q=qi][dc*32 + hi*8 + 0..7]
  uint4 qfr[5];
  #pragma unroll
  for (int dc = 0; dc < 5; ++dc)
    qfr[dc] = *(const uint4*)(qg + (size_t)qi*160 + dc*32 + hi*8);

  f32x4 o[9];
  #pragma unroll
  for (int d = 0; d < 9; ++d) o[d] = f32x4{0.f,0.f,0.f,0.f};
  float m = -INFINITY, l = 0.f;

  const int krow = t >> 2;       // 0..63 staging row
  const int kc4  = t & 3;

  for (int kt = 0; kt < 32; ++kt) {
    __syncthreads();
    // ---- stage K (row-major, stride 168) ----
    const u16* ksrc = kg + ((size_t)(kt*64 + krow)) * 160;
    #pragma unroll
    for (int i = 0; i < 5; ++i) {
      const int c = kc4 + 4*i;
      *(uint4*)&Ks[krow][c*8] = *(const uint4*)(ksrc + c*8);
    }
    // ---- stage V transposed (Vt[d][k], d<144 only) ----
    const u16* vsrc = vg + ((size_t)(kt*64 + krow)) * 160;
    #pragma unroll
    for (int i = 0; i < 9; ++i) {
      const int c = kc4 + 4*i;
      const uint2 vv = *(const uint2*)(vsrc + c*4);
      Vt[c*4+0][krow] = (u16)(vv.x & 0xffffu);
      Vt[c*4+1][krow] = (u16)(vv.x >> 16);
      Vt[c*4+2][krow] = (u16)(vv.y & 0xffffu);
      Vt[c*4+3][krow] = (u16)(vv.y >> 16);
    }
    __syncthreads();

    // ---- S^T = K * Q^T : lane holds S^T[k = ks*16 + 4*hi + r][q = qi] ----
    f32x4 st[4];
    #pragma unroll
    for (int ks = 0; ks < 4; ++ks) {
      st[ks] = f32x4{0.f,0.f,0.f,0.f};
      #pragma unroll
      for (int dc = 0; dc < 5; ++dc) {
        const uint4 kf4 = *(const uint4*)&Ks[ks*16 + qi][dc*32 + hi*8];
        st[ks] = mfma_bf16(kf4, qfr[dc], st[ks]);
      }
    }

    // ---- online softmax over k (per q = qi) ----
    float pm = st[0][0];
    #pragma unroll
    for (int ks = 0; ks < 4; ++ks)
      #pragma unroll
      for (int r = 0; r < 4; ++r) pm = fmaxf(pm, st[ks][r]);
    pm = fmaxf(pm, __shfl_xor(pm, 16));
    pm = fmaxf(pm, __shfl_xor(pm, 32));
    const float mn = fmaxf(m, pm);
    const float rs = __expf(m - mn);
    float ts = 0.f;
    #pragma unroll
    for (int ks = 0; ks < 4; ++ks)
      #pragma unroll
      for (int r = 0; r < 4; ++r) {
        const float p = __expf(st[ks][r] - mn);
        st[ks][r] = p;
        ts += p;
      }
    ts += __shfl_xor(ts, 16);
    ts += __shfl_xor(ts, 32);
    l = l*rs + ts;
    m = mn;
    #pragma unroll
    for (int d = 0; d < 9; ++d)
      #pragma unroll
      for (int r = 0; r < 4; ++r) o[d][r] *= rs;

    // ---- P -> bf16 frags (lane-local) ----
    uint4 pb[2];
    #pragma unroll
    for (int s = 0; s < 2; ++s) {
      pb[s].x = pack2(st[2*s][0],   st[2*s][1]);
      pb[s].y = pack2(st[2*s][2],   st[2*s][3]);
      pb[s].z = pack2(st[2*s+1][0], st[2*s+1][1]);
      pb[s].w = pack2(st[2*s+1][2], st[2*s+1][3]);
    }

    // ---- O^T += V^T * P^T : lane holds O^T[d = ds*16 + 4*hi + r][q = qi] ----
    #pragma unroll
    for (int ds = 0; ds < 9; ++ds) {
      const u16* vrow = &Vt[ds*16 + qi][0];
      #pragma unroll
      for (int s = 0; s < 2; ++s) {
        const uint2 a0 = *(const uint2*)(vrow + s*32 + hi*4);
        const uint2 a1 = *(const uint2*)(vrow + s*32 + 16 + hi*4);
        o[ds] = mfma_bf16(uint4{a0.x, a0.y, a1.x, a1.y}, pb[s], o[ds]);
      }
    }
  }

  // ---- epilogue: transpose O via LDS, coalesced f32 store ----
  const float inv = hsc[h] / l;
  float* Ol = (float*)smem;    // [64][148]
  __syncthreads();
  #pragma unroll
  for (int ds = 0; ds < 9; ++ds)
    #pragma unroll
    for (int r = 0; r < 4; ++r)
      Ol[(w*16 + qi)*148 + ds*16 + hi*4 + r] = o[ds][r] * inv;
  __syncthreads();
  const size_t hobase = (((size_t)b*2048 + qt*64)*8 + h)*144;
  for (int idx = t; idx < 64*36; idx += 256) {
    const int q = idx / 36, c = idx - q*36;
    *(float4*)(ho + hobase + (size_t)q*1152 + c*4) = *(const float4*)&Ol[q*148 + c*4];
  }
}

// ---------------------------------------------------------------------------
// Output projection: 2 tokens / 256-thread block, 1 thread per mv output.
// ---------------------------------------------------------------------------
__global__ __launch_bounds__(256) void k_out(
    const float* __restrict__ ho,
    const float* __restrict__ w_mv, const float* __restrict__ w_s2mv,
    const float* __restrict__ w_mv2s, const float* __restrict__ w_s,
    float* __restrict__ out)
{
  __shared__ float lh[2304];   // 2 tokens x 8 heads x 144
  __shared__ float ob[512];
  const int t = threadIdx.x;
  const size_t tok0 = (size_t)blockIdx.x * 2;
  const float* hp0 = ho + tok0 * 1152;
  for (int idx = t; idx < 576; idx += 256)
    *(float4*)&lh[idx*4] = *(const float4*)&hp0[idx*4];
  __syncthreads();

  // Phase B: 512 mv outputs (tok, o, x)
  #pragma unroll
  for (int rep = 0; rep < 2; ++rep) {
    const int oi = t + rep*256;
    const int tok = oi >> 8, o = (oi >> 4) & 15, x = oi & 15;
    const float* wp = w_mv + (kG[x]*16 + o)*64;
    const float* hp = lh + tok*1152 + x;
    float acc = 0.f;
    #pragma unroll 8
    for (int mc = 0; mc < 64; ++mc)
      acc += hp[(mc >> 3)*144 + (mc & 7)*16] * wp[mc];
    ob[oi] = acc;
  }
  __syncthreads();

  // Phase C: scalars -> grade-0 of mv outputs (32 outputs x 8 partials)
  {
    const int oi = t >> 3, part = t & 7;
    const int tok = oi >> 4, o = oi & 15;
    const float* hp = lh + tok*1152;
    float a = 0.f;
    #pragma unroll
    for (int j = 0; j < 16; ++j) {
      const int ms = part*16 + j;
      a += hp[(ms >> 4)*144 + 128 + (ms & 15)] * w_s2mv[o*128 + ms];
    }
    a += __shfl_xor(a, 1); a += __shfl_xor(a, 2); a += __shfl_xor(a, 4);
    if (part == 0) ob[tok*256 + o*16] += a;
  }

  // Phase D: 64 scalar outputs x 4 partials
  {
    const int oi = t >> 2, part = t & 3;
    const int tok = oi >> 5, o2 = oi & 31;
    const float* hp = lh + tok*1152;
    float a = 0.f;
    #pragma unroll
    for (int j = 0; j < 32; ++j) {
      const int ms = part*32 + j;
      a += hp[(ms >> 4)*144 + 128 + (ms & 15)] * w_s[o2*128 + ms];
    }
    #pragma unroll
    for (int j = 0; j < 16; ++j) {
      const int mc = part*16 + j;
      a += hp[(mc >> 3)*144 + (mc & 7)*16] * w_mv2s[o2*64 + mc];
    }
    a += __shfl_xor(a, 1); a += __shfl_xor(a, 2);
    if (part == 0) out[2097152 + (tok0 + tok)*32 + o2] = a;
  }
  __syncthreads();

  // Phase E: coalesced mv store
  out[tok0*256 + t]       = ob[t];
  out[tok0*256 + 256 + t] = ob[256 + t];
}

// ---------------------------------------------------------------------------
extern "C" void kernel_launch(void* const* d_in, const int* in_sizes, int n_in,
                              void* d_out, int out_size, void* d_ws, size_t ws_size,
                              hipStream_t stream) {
  const float* mv_kv    = (const float*)d_in[0];
  const float* mv_q     = (const float*)d_in[1];
  const float* s_kv     = (const float*)d_in[2];
  const float* s_q      = (const float*)d_in[3];
  const float* w_mv_q   = (const float*)d_in[4];
  const float* w_s2mv_q = (const float*)d_in[5];
  const float* w_mv2s_q = (const float*)d_in[6];
  const float* w_s_q    = (const float*)d_in[7];
  const float* w_mv_kv   = (const float*)d_in[8];
  const float* w_s2mv_kv = (const float*)d_in[9];
  const float* w_mv2s_kv = (const float*)d_in[10];
  const float* w_s_kv    = (const float*)d_in[11];
  const float* w_mv_o   = (const float*)d_in[12];
  const float* w_s2mv_o = (const float*)d_in[13];
  const float* w_mv2s_o = (const float*)d_in[14];
  const float* w_s_o    = (const float*)d_in[15];
  const float* hscale   = (const float*)d_in[16];

  // ws: qf, kf, vf bf16 (4*8*2048*160 = 10485760 u16 each), ho f32 (9437184)
  u16* qf = (u16*)d_ws;
  u16* kf = qf + 10485760;
  u16* vf = kf + 10485760;
  float* ho = (float*)(vf + 10485760);

  k_proj_q <<<8192, 192, 0, stream>>>(mv_q,  s_q,  w_mv_q,  w_s2mv_q,  w_mv2s_q,  w_s_q,  qf);
  k_proj_kv<<<8192, 384, 0, stream>>>(mv_kv, s_kv, w_mv_kv, w_s2mv_kv, w_mv2s_kv, w_s_kv, kf, vf);
  k_attn   <<<1024, 256, 0, stream>>>(qf, kf, vf, hscale, ho);
  k_out    <<<4096, 256, 0, stream>>>(ho, w_mv_o, w_s2mv_o, w_mv2s_o, w_s_o, (float*)d_out);
}